// Round 17
// baseline (112.730 us; speedup 1.0000x reference)
//
#include <hip/hip_runtime.h>
#include <math.h>

#define BB 16384      // B
#define CC 50         // clusters
#define KK 128        // top-K
#define DD 128        // feature dim
#define MM 12800      // CC*2*KK rows of F
#define NBLK 100      // 128-row blocks of F
#define NCHUNK 13     // J-chunks per row (chunk = 8 tiles)
#define CHT 8         // tiles per chunk
#define MAXCAND 2048
#define TCAND 0.97f
#define NPART 64      // candidate partitions (256 rows each)
#define RPP 256       // rows per partition
#define PCAP 32       // per (partition,cluster) capacity; expected ~7.7
#define GSUB 4        // sub-blocks per cluster in selgather (redundant select)
// F rows pre-scaled by SQS = sqrt(2/ln2): dot(F,F) = sim*2/ln2 -> exp2 direct.
// Single bf16 product (validated r8-r16: absmax 0.0 vs reference).
#define SQS 1.6986436f

// Tiled F layout: for each 32-row group G (400 groups), each kc (16-K chunk,
// 8 chunks), 64 granules of 16B lane-ordered for mfma_32x32x16_bf16 operands.
// One fragment load = contiguous 1KB wave load at G*8192 + kc*1024 + lane*16.
//
// LESSON (r13/r14): intra-kernel producer->consumer sync costs a per-block
// device-fence L2-writeback tax — keep pipeline stages as separate nodes.
// LESSON (r16): node count 4 vs 5 makes no difference -> per-node overhead is
// small; the kernel-time sum dominates. sim_sym (~40us at ~25% util) is the
// remaining fish: this round gives it 4-waves/block TLP + LDS-shared B.

typedef __bf16 bf16x8 __attribute__((ext_vector_type(8)));
typedef float f32x16 __attribute__((ext_vector_type(16)));

#define MFMA32(a, b, c) __builtin_amdgcn_mfma_f32_32x32x16_bf16(a, b, c, 0, 0, 0)

__device__ inline unsigned short f2bf(float x) {
  unsigned u = __float_as_uint(x);
  unsigned r = (u + 0x7fffu + ((u >> 16) & 1u)) >> 16;
  return (unsigned short)r;
}

// ---------------------------------------------------------------------------
// Kernel 1: candidate collection (r9, validated). Zeroes the finalize ticket.
// ---------------------------------------------------------------------------
__global__ void cand_kernel(const float* __restrict__ prob, int* __restrict__ candCnt,
                            int* __restrict__ candIdx, float* __restrict__ candVal,
                            int* __restrict__ ticket) {
  __shared__ int lcnt[CC];
  const int b = blockIdx.x, t = threadIdx.x;
  if (b == 0 && t == 0) *ticket = 0;
  if (t < CC) lcnt[t] = 0;
  __syncthreads();
  const int base = b * RPP * CC;
  for (int i = t; i < RPP * CC; i += 256) {
    const float v = prob[base + i];
    if (v >= TCAND) {
      const int r = i / CC, c = i - r * CC;
      const int slot = atomicAdd(&lcnt[c], 1);
      if (slot < PCAP) {
        candIdx[(b * CC + c) * PCAP + slot] = b * RPP + r;
        candVal[(b * CC + c) * PCAP + slot] = v;
      }
    }
  }
  __syncthreads();
  if (t < CC) candCnt[b * CC + t] = lcnt[t];
}

// ---------------------------------------------------------------------------
// PARALLEL bin selection (r12, validated).
// ---------------------------------------------------------------------------
#define PICK_BIN()                                                             \
  {                                                                            \
    _Pragma("unroll")                                                          \
    for (int d = 1; d < 256; d <<= 1) {                                        \
      int v = (t + d < 256) ? hist[t + d] : 0;                                 \
      __syncthreads();                                                         \
      hist[t] += v;                                                            \
      __syncthreads();                                                         \
    }                                                                          \
    const int Sb = hist[t];                                                    \
    const int Sb1 = (t == 255) ? 0 : hist[t + 1];                              \
    if (Sb >= krem && Sb1 < krem) { sChosen = t; sKrem = krem - Sb1; }         \
    __syncthreads();                                                           \
  }

// Deterministic scan-based compaction (r16, validated).
#define COMPACT_DET(TOTAL, GETU, GETI)                                         \
  {                                                                            \
    const int chunk = ((TOTAL) + 255) >> 8;                                    \
    const int j0 = t * chunk;                                                  \
    const int j1 = (j0 + chunk < (TOTAL)) ? j0 + chunk : (TOTAL);              \
    int myGt = 0, myEq = 0;                                                    \
    for (int j = j0; j < j1; ++j) {                                            \
      unsigned u = (GETU);                                                     \
      myGt += (u > T) ? 1 : 0; myEq += (u == T) ? 1 : 0;                       \
    }                                                                          \
    hist[t] = (myGt << 16) | myEq;                                             \
    __syncthreads();                                                           \
    _Pragma("unroll")                                                          \
    for (int d = 1; d < 256; d <<= 1) {                                        \
      int v = (t >= d) ? hist[t - d] : 0;                                      \
      __syncthreads();                                                         \
      hist[t] += v;                                                            \
      __syncthreads();                                                         \
    }                                                                          \
    const int incl = hist[t];                                                  \
    const int gtCount = (hist[255] >> 16) & 0xffff;                            \
    const int eqTotal = hist[255] & 0xffff;                                    \
    int pg = ((incl >> 16) & 0xffff) - myGt;                                   \
    int pe = (incl & 0xffff) - myEq;                                           \
    for (int j = j0; j < j1; ++j) {                                            \
      unsigned u = (GETU);                                                     \
      if (u > T) topkL[pg++] = (GETI);                                         \
      else if (u == T) { if (pe < 256) eqIdx[pe] = (GETI); pe++; }             \
    }                                                                          \
    __syncthreads();                                                           \
    if (t == 0) {                                                              \
      int krem2 = KK - gtCount;                                                \
      int ec = eqTotal < 256 ? eqTotal : 256;                                  \
      for (int j2 = 0; j2 < krem2; ++j2) {                                     \
        int bi = -1, bv = 0x7fffffff;                                          \
        for (int q = 0; q < ec; ++q) {                                         \
          int v = eqIdx[q];                                                    \
          if (v >= 0 && v < bv) { bv = v; bi = q; }                            \
        }                                                                      \
        topkL[gtCount + j2] = bv;                                              \
        eqIdx[bi] = -1;                                                        \
      }                                                                        \
    }                                                                          \
  }

// ---------------------------------------------------------------------------
// Kernel 2: FUSED top-K select + gather/norm, GSUB blocks/cluster (r16, valid).
// ---------------------------------------------------------------------------
__global__ void selgather_kernel(const float* __restrict__ prob,
                                 const int* __restrict__ candCnt,
                                 const int* __restrict__ candIdx,
                                 const float* __restrict__ candVal,
                                 const float* __restrict__ zi,
                                 const float* __restrict__ zj,
                                 char* __restrict__ FT) {
  __shared__ float vals[MAXCAND];
  __shared__ int   idxs[MAXCAND];
  __shared__ int hist[256];
  __shared__ int pref[NPART + 1];
  __shared__ int cntL[NPART];
  __shared__ int topkL[KK];
  __shared__ int eqIdx[256];
  __shared__ int sChosen, sKrem, bad;
  const int c = blockIdx.x / GSUB, g = blockIdx.x - c * GSUB;
  const int t = threadIdx.x;

  if (t == 0) bad = 0;
  __syncthreads();
  if (t < NPART) {
    int cnt_p = candCnt[t * CC + c];
    cntL[t] = cnt_p;
    if (cnt_p > PCAP) bad = 1;
    int x = cnt_p;
#pragma unroll
    for (int d = 1; d < 64; d <<= 1) {
      int y = __shfl_up(x, d, 64);
      if (t >= d) x += y;
    }
    pref[t + 1] = x;
    if (t == 0) pref[0] = 0;
  }
  __syncthreads();
  const int total = pref[NPART];

  if (!bad && total >= KK && total <= MAXCAND) {
    for (int idx = t; idx < NPART * PCAP; idx += 256) {
      const int pt = idx >> 5, sl = idx & 31;
      if (sl < cntL[pt]) {
        const int o = pref[pt] + sl;
        vals[o] = candVal[(pt * CC + c) * PCAP + sl];
        idxs[o] = candIdx[(pt * CC + c) * PCAP + sl];
      }
    }
    __syncthreads();
    unsigned prefix = 0;
    int krem = KK;
    for (int pass = 0; pass < 4; ++pass) {
      const int shift = 24 - pass * 8;
      hist[t] = 0;
      __syncthreads();
      for (int j = t; j < total; j += 256) {
        unsigned u = __float_as_uint(vals[j]);
        bool match = (pass == 0) || ((u >> (shift + 8)) == (prefix >> (shift + 8)));
        if (match) atomicAdd(&hist[(u >> shift) & 255], 1);
      }
      __syncthreads();
      PICK_BIN()
      prefix |= ((unsigned)sChosen) << shift;
      krem = sKrem;
      __syncthreads();
    }
    const unsigned T = prefix;
    COMPACT_DET(total, __float_as_uint(vals[j]), idxs[j])
  } else {
    unsigned prefix = 0;
    int krem = KK;
    for (int pass = 0; pass < 4; ++pass) {
      const int shift = 24 - pass * 8;
      hist[t] = 0;
      __syncthreads();
      for (int i = t; i < BB; i += 256) {
        unsigned u = __float_as_uint(prob[i * CC + c]);
        bool match = (pass == 0) || ((u >> (shift + 8)) == (prefix >> (shift + 8)));
        if (match) atomicAdd(&hist[(u >> shift) & 255], 1);
      }
      __syncthreads();
      PICK_BIN()
      prefix |= ((unsigned)sChosen) << shift;
      krem = sKrem;
      __syncthreads();
    }
    const unsigned T = prefix;
    COMPACT_DET(BB, __float_as_uint(prob[(size_t)j * CC + c]), j)
  }

  // ---- Phase 2: gather rows [g*64, g*64+64); wave-per-row, 16 rows/wave ----
  __syncthreads();
  const int lane = t & 63, wv = t >> 6;
#pragma unroll 4
  for (int it = 0; it < 16; ++it) {
    const int p = g * 64 + wv * 16 + it;
    const int idx = topkL[p & (KK - 1)];
    const float* src = (p < KK ? zi : zj) + (size_t)idx * DD;
    float2 v = ((const float2*)src)[lane];
    float ss = fmaf(v.x, v.x, v.y * v.y);
#pragma unroll
    for (int m = 1; m < 64; m <<= 1) ss += __shfl_xor(ss, m, 64);
    const float scale = SQS / fmaxf(sqrtf(ss), 1e-8f);
    unsigned short ah = f2bf(v.x * scale), bh = f2bf(v.y * scale);
    unsigned hp = ((unsigned)bh << 16) | ah;
    const int gw = c * 256 + p;
    const int k2 = 2 * lane;
    const int kc = k2 >> 4;
    const int kk = k2 & 15;
    const size_t off = (size_t)(gw >> 5) * 8192 + (size_t)kc * 1024 +
                       (size_t)(((kk >> 3) * 32 + (gw & 31)) * 16 + (kk & 7) * 2);
    *(unsigned*)(FT + off) = hp;
  }
}

// ---------------------------------------------------------------------------
// Kernel 3: PANELIZED symmetric sim, RESTRUCTURED: 256-thread blocks, 4 waves
// each owning ONE 32-row A-group; B column-groups staged once per cg into LDS
// (8KB, double-buffered, async-STAGE: next-cg global loads issued before the
// MFMAs, ds_write after). Regs drop (~110) -> 3-4 waves/SIMD; epilogue and
// load latency hide under other waves' MFMA. Semantics identical to r16.
// ---------------------------------------------------------------------------
__global__ __launch_bounds__(256, 2) void sim_sym_kernel(
    const char* __restrict__ F, float* __restrict__ part,
    float* __restrict__ ownArr, float* __restrict__ posArr) {
  __shared__ __align__(16) char Bst[2][8192];
  __shared__ float colLds[4][1024];
  const int tid = threadIdx.x;
  const int lane = tid & 63, wave = tid >> 6;     // wave 0..3
  const int lh2 = lane >> 5;
  const size_t lo16 = (size_t)lane * 16;
  f32x16 Z = {};

  if (blockIdx.x < NBLK * NCHUNK) {
    const int I = blockIdx.x / NCHUNK, q = blockIdx.x - I * NCHUNK;
    const int J0 = I + q * CHT;
    if (J0 >= NBLK) return;
    const int nt = min(CHT, NBLK - J0);
    const int S = nt * 4;
    const int G0 = J0 * 4;
    const int Ga = I * 4 + wave;                  // one group per wave

    bf16x8 A[8];
#pragma unroll
    for (int kc = 0; kc < 8; ++kc)
      A[kc] = *(const bf16x8*)(F + (size_t)Ga * 8192 + kc * 1024 + lo16);

    float rAcc[16];
#pragma unroll
    for (int r = 0; r < 16; ++r) rAcc[r] = 0.f;

    // prologue: stage cg0 into Bst[0] (wave w covers kc 2w, 2w+1)
    {
      const char* g = F + (size_t)G0 * 8192;
      float4 r0 = *(const float4*)(g + (2 * wave) * 1024 + lo16);
      float4 r1 = *(const float4*)(g + (2 * wave + 1) * 1024 + lo16);
      *(float4*)(Bst[0] + (2 * wave) * 1024 + lo16) = r0;
      *(float4*)(Bst[0] + (2 * wave + 1) * 1024 + lo16) = r1;
    }
    __syncthreads();

    for (int s = 0; s < S; ++s) {
      const int cur = s & 1;
      float4 n0, n1;
      const bool more = (s + 1 < S);
      if (more) {                                  // issue next-cg loads EARLY
        const char* g = F + (size_t)(G0 + s + 1) * 8192;
        n0 = *(const float4*)(g + (2 * wave) * 1024 + lo16);
        n1 = *(const float4*)(g + (2 * wave + 1) * 1024 + lo16);
      }
      f32x16 acc = Z;
#pragma unroll
      for (int kc = 0; kc < 8; ++kc) {
        bf16x8 b = *(const bf16x8*)(Bst[cur] + kc * 1024 + lo16);
        acc = MFMA32(A[kc], b, acc);
      }
      float colv = 0.f;
#pragma unroll
      for (int r = 0; r < 16; ++r) {
        float e = __builtin_amdgcn_exp2f(acc[r]);
        rAcc[r] += e;
        colv += e;
      }
      {
        float cv = colv + __shfl_xor(colv, 32, 64);
        if (lane < 32) colLds[wave][s * 32 + lane] = cv;
      }
      if (more) {                                  // write next buffer LATE
        *(float4*)(Bst[cur ^ 1] + (2 * wave) * 1024 + lo16) = n0;
        *(float4*)(Bst[cur ^ 1] + (2 * wave + 1) * 1024 + lo16) = n1;
      }
      __syncthreads();                             // buf ready; gates restage
    }

    // batched col-sum write (sum 4 waves; skip diagonal tile J==I)
    for (int idx = tid; idx < S * 32; idx += 256) {
      const int J = J0 + (idx >> 7);
      if (J != I)
        part[(size_t)I * MM + J * 128 + (idx & 127)] =
            colLds[0][idx] + colLds[1][idx] + colLds[2][idx] + colLds[3][idx];
    }

    // panel row-sums -> slot NBLK+q
#pragma unroll
    for (int m = 1; m < 32; m <<= 1)
#pragma unroll
      for (int r = 0; r < 16; ++r) rAcc[r] += __shfl_xor(rAcc[r], m, 32);
    if ((lane & 31) == 0) {
      const int rbase = I * 128 + wave * 32;
#pragma unroll
      for (int r = 0; r < 16; ++r) {
        const int rl = (r & 3) + 8 * (r >> 2) + 4 * lh2;
        part[(size_t)(NBLK + q) * MM + rbase + rl] = rAcc[r];
      }
    }
  } else {
    // ===== own/pos path: (c, half) blocks, 4 waves x 1 group, S=8 =====
    const int bid2 = blockIdx.x - NBLK * NCHUNK;   // 0..199
    const int c = bid2 >> 1, half = bid2 & 1;
    const int Ga = c * 8 + half * 4 + wave;        // rows c*256+half*128+wave*32
    const int G0 = c * 8;

    bf16x8 A[8];
#pragma unroll
    for (int kc = 0; kc < 8; ++kc)
      A[kc] = *(const bf16x8*)(F + (size_t)Ga * 8192 + kc * 1024 + lo16);

    float rOwn[16], rPos[16];
#pragma unroll
    for (int r = 0; r < 16; ++r) { rOwn[r] = 0.f; rPos[r] = 0.f; }

    {
      const char* g = F + (size_t)G0 * 8192;
      float4 r0 = *(const float4*)(g + (2 * wave) * 1024 + lo16);
      float4 r1 = *(const float4*)(g + (2 * wave + 1) * 1024 + lo16);
      *(float4*)(Bst[0] + (2 * wave) * 1024 + lo16) = r0;
      *(float4*)(Bst[0] + (2 * wave + 1) * 1024 + lo16) = r1;
    }
    __syncthreads();

    for (int s = 0; s < 8; ++s) {
      const int cur = s & 1;
      float4 n0, n1;
      const bool more = (s + 1 < 8);
      if (more) {
        const char* g = F + (size_t)(G0 + s + 1) * 8192;
        n0 = *(const float4*)(g + (2 * wave) * 1024 + lo16);
        n1 = *(const float4*)(g + (2 * wave + 1) * 1024 + lo16);
      }
      f32x16 acc = Z;
#pragma unroll
      for (int kc = 0; kc < 8; ++kc) {
        bf16x8 b = *(const bf16x8*)(Bst[cur] + kc * 1024 + lo16);
        acc = MFMA32(A[kc], b, acc);
      }
      const bool isPos = (s < 4);
#pragma unroll
      for (int r = 0; r < 16; ++r) {
        float e = __builtin_amdgcn_exp2f(acc[r]);
        rOwn[r] += e;
        if (isPos) rPos[r] += e;
      }
      if (more) {
        *(float4*)(Bst[cur ^ 1] + (2 * wave) * 1024 + lo16) = n0;
        *(float4*)(Bst[cur ^ 1] + (2 * wave + 1) * 1024 + lo16) = n1;
      }
      __syncthreads();
    }

#pragma unroll
    for (int m = 1; m < 32; m <<= 1)
#pragma unroll
      for (int r = 0; r < 16; ++r) {
        rOwn[r] += __shfl_xor(rOwn[r], m, 32);
        rPos[r] += __shfl_xor(rPos[r], m, 32);
      }
    if ((lane & 31) == 0) {
      const int rbase = c * 256 + half * 128 + wave * 32;
#pragma unroll
      for (int r = 0; r < 16; ++r) {
        const int rl = (r & 3) + 8 * (r >> 2) + 4 * lh2;
        ownArr[rbase + rl] = rOwn[r];
        posArr[rbase + rl] = rPos[r];
      }
    }
  }
}

// ---------------------------------------------------------------------------
// Kernel 4: per-row loss + block reduction + last-block mean via ticket
// (r12/r16, validated; ticket contention is only 50 blocks).
// ---------------------------------------------------------------------------
__global__ void finalize_kernel(const float* __restrict__ part,
                                const float* __restrict__ ownArr,
                                const float* __restrict__ posArr,
                                float* __restrict__ partial,
                                int* __restrict__ ticket,
                                float* __restrict__ out) {
  __shared__ float red[4];
  const int t = threadIdx.x;
  const int p = blockIdx.x * 256 + t;
  const int pb = p >> 7;
  float a = 0.f;
  for (int b = 0; b < pb; ++b) a += part[(size_t)b * MM + p];
  const int qmax = (NBLK - 1 - pb) >> 3;
  for (int q = 0; q <= qmax; ++q) a += part[(size_t)(NBLK + q) * MM + p];
  float rl = logf(a - ownArr[p]) - logf(posArr[p]);
#pragma unroll
  for (int m = 1; m < 64; m <<= 1) rl += __shfl_xor(rl, m, 64);
  if ((t & 63) == 0) red[t >> 6] = rl;
  __syncthreads();
  if (t == 0) {
    const float bsum = red[0] + red[1] + red[2] + red[3];
    __hip_atomic_store(&partial[blockIdx.x], bsum, __ATOMIC_RELEASE,
                       __HIP_MEMORY_SCOPE_AGENT);
    const int old = __hip_atomic_fetch_add(ticket, 1, __ATOMIC_ACQ_REL,
                                           __HIP_MEMORY_SCOPE_AGENT);
    if (old == (MM / 256) - 1) {
      float s = 0.f;
      for (int i = 0; i < MM / 256; ++i)
        s += __hip_atomic_load(&partial[i], __ATOMIC_ACQUIRE,
                               __HIP_MEMORY_SCOPE_AGENT);
      out[0] = s * (1.0f / MM);
    }
  }
}

extern "C" void kernel_launch(void* const* d_in, const int* in_sizes, int n_in,
                              void* d_out, int out_size, void* d_ws, size_t ws_size,
                              hipStream_t stream) {
  const float* prob = (const float*)d_in[0];
  const float* zi   = (const float*)d_in[1];
  const float* zj   = (const float*)d_in[2];
  float* out = (float*)d_out;

  char* ws = (char*)d_ws;
  char*  FT       = ws;                                  // 3,276,800 B
  float* part     = (float*)(ws + 3276800);              // 113*12800*4 = 5,785,600 B
  // cand buffers alias the (not-yet-live) part region: dead before sim writes.
  int*   candCnt  = (int*)  (ws + 3276800);              //    12,800 B
  int*   candIdx  = (int*)  (ws + 3276800 + 16384);      //   409,600 B
  float* candVal  = (float*)(ws + 3276800 + 430080);     //   409,600 B
  float* ownArr   = (float*)(ws + 9062400);              //    51,200 B
  float* posArr   = (float*)(ws + 9113600);              //    51,200 B
  float* partial  = (float*)(ws + 9164800);              //       256 B
  int*   ticket   = (int*)  (ws + 9165056);              //         4 B

  cand_kernel     <<<NPART, 256, 0, stream>>>(prob, candCnt, candIdx, candVal, ticket);
  selgather_kernel<<<CC * GSUB, 256, 0, stream>>>(prob, candCnt, candIdx, candVal, zi, zj, FT);
  sim_sym_kernel  <<<NBLK * NCHUNK + 2 * CC, 256, 0, stream>>>(FT, part, ownArr, posArr);
  finalize_kernel <<<MM / 256, 256, 0, stream>>>(part, ownArr, posArr, partial, ticket, out);
}

// Round 18
// 108.788 us; speedup vs baseline: 1.0362x; 1.0362x over previous
//
#include <hip/hip_runtime.h>
#include <math.h>

#define BB 16384      // B
#define CC 50         // clusters
#define KK 128        // top-K
#define DD 128        // feature dim
#define MM 12800      // CC*2*KK rows of F
#define NBLK 100      // 128-row blocks of F
#define NCHUNK 13     // J-chunks per row (chunk = 8 tiles)
#define CHT 8         // tiles per chunk
#define MAXCAND 2048
#define TCAND 0.97f
#define NPART 64      // candidate partitions (256 rows each)
#define RPP 256       // rows per partition
#define PCAP 32       // per (partition,cluster) capacity; expected ~7.7
#define GSUB 4        // sub-blocks per cluster in selgather (redundant select)
// F rows pre-scaled by SQS = sqrt(2/ln2): dot(F,F) = sim*2/ln2 -> exp2 direct.
// Single bf16 product (validated r8-r17: absmax 0.0 vs reference).
#define SQS 1.6986436f

// Tiled F layout: for each 32-row group G (400 groups), each kc (16-K chunk,
// 8 chunks), 64 granules of 16B lane-ordered for mfma_32x32x16_bf16 operands.
// One fragment load = contiguous 1KB wave load at G*8192 + kc*1024 + lane*16.
//
// LESSON (r13/r14): intra-kernel producer->consumer sync costs a per-block
// device-fence L2-writeback tax — keep pipeline stages as separate nodes.
// LESSON (r16/r17): sim at ~43us/20% util was phase-lock (per-cg barriers put
// LDS+epilogue on the critical path) OR 1 wave/SIMD (serial MFMA chain
// exposed). This round: barrier-free B (global+L1 broadcast), two independent
// accumulator chains per wave, 3 blocks/CU.

typedef __bf16 bf16x8 __attribute__((ext_vector_type(8)));
typedef float f32x16 __attribute__((ext_vector_type(16)));

#define MFMA32(a, b, c) __builtin_amdgcn_mfma_f32_32x32x16_bf16(a, b, c, 0, 0, 0)

__device__ inline unsigned short f2bf(float x) {
  unsigned u = __float_as_uint(x);
  unsigned r = (u + 0x7fffu + ((u >> 16) & 1u)) >> 16;
  return (unsigned short)r;
}

// ---------------------------------------------------------------------------
// Kernel 1: candidate collection (r9, validated). Zeroes the finalize ticket.
// ---------------------------------------------------------------------------
__global__ void cand_kernel(const float* __restrict__ prob, int* __restrict__ candCnt,
                            int* __restrict__ candIdx, float* __restrict__ candVal,
                            int* __restrict__ ticket) {
  __shared__ int lcnt[CC];
  const int b = blockIdx.x, t = threadIdx.x;
  if (b == 0 && t == 0) *ticket = 0;
  if (t < CC) lcnt[t] = 0;
  __syncthreads();
  const int base = b * RPP * CC;
  for (int i = t; i < RPP * CC; i += 256) {
    const float v = prob[base + i];
    if (v >= TCAND) {
      const int r = i / CC, c = i - r * CC;
      const int slot = atomicAdd(&lcnt[c], 1);
      if (slot < PCAP) {
        candIdx[(b * CC + c) * PCAP + slot] = b * RPP + r;
        candVal[(b * CC + c) * PCAP + slot] = v;
      }
    }
  }
  __syncthreads();
  if (t < CC) candCnt[b * CC + t] = lcnt[t];
}

// ---------------------------------------------------------------------------
// PARALLEL bin selection (r12, validated).
// ---------------------------------------------------------------------------
#define PICK_BIN()                                                             \
  {                                                                            \
    _Pragma("unroll")                                                          \
    for (int d = 1; d < 256; d <<= 1) {                                        \
      int v = (t + d < 256) ? hist[t + d] : 0;                                 \
      __syncthreads();                                                         \
      hist[t] += v;                                                            \
      __syncthreads();                                                         \
    }                                                                          \
    const int Sb = hist[t];                                                    \
    const int Sb1 = (t == 255) ? 0 : hist[t + 1];                              \
    if (Sb >= krem && Sb1 < krem) { sChosen = t; sKrem = krem - Sb1; }         \
    __syncthreads();                                                           \
  }

// Deterministic scan-based compaction (r16, validated).
#define COMPACT_DET(TOTAL, GETU, GETI)                                         \
  {                                                                            \
    const int chunk = ((TOTAL) + 255) >> 8;                                    \
    const int j0 = t * chunk;                                                  \
    const int j1 = (j0 + chunk < (TOTAL)) ? j0 + chunk : (TOTAL);              \
    int myGt = 0, myEq = 0;                                                    \
    for (int j = j0; j < j1; ++j) {                                            \
      unsigned u = (GETU);                                                     \
      myGt += (u > T) ? 1 : 0; myEq += (u == T) ? 1 : 0;                       \
    }                                                                          \
    hist[t] = (myGt << 16) | myEq;                                             \
    __syncthreads();                                                           \
    _Pragma("unroll")                                                          \
    for (int d = 1; d < 256; d <<= 1) {                                        \
      int v = (t >= d) ? hist[t - d] : 0;                                      \
      __syncthreads();                                                         \
      hist[t] += v;                                                            \
      __syncthreads();                                                         \
    }                                                                          \
    const int incl = hist[t];                                                  \
    const int gtCount = (hist[255] >> 16) & 0xffff;                            \
    const int eqTotal = hist[255] & 0xffff;                                    \
    int pg = ((incl >> 16) & 0xffff) - myGt;                                   \
    int pe = (incl & 0xffff) - myEq;                                           \
    for (int j = j0; j < j1; ++j) {                                            \
      unsigned u = (GETU);                                                     \
      if (u > T) topkL[pg++] = (GETI);                                         \
      else if (u == T) { if (pe < 256) eqIdx[pe] = (GETI); pe++; }             \
    }                                                                          \
    __syncthreads();                                                           \
    if (t == 0) {                                                              \
      int krem2 = KK - gtCount;                                                \
      int ec = eqTotal < 256 ? eqTotal : 256;                                  \
      for (int j2 = 0; j2 < krem2; ++j2) {                                     \
        int bi = -1, bv = 0x7fffffff;                                          \
        for (int q = 0; q < ec; ++q) {                                         \
          int v = eqIdx[q];                                                    \
          if (v >= 0 && v < bv) { bv = v; bi = q; }                            \
        }                                                                      \
        topkL[gtCount + j2] = bv;                                              \
        eqIdx[bi] = -1;                                                        \
      }                                                                        \
    }                                                                          \
  }

// ---------------------------------------------------------------------------
// Kernel 2: FUSED top-K select + gather/norm, GSUB blocks/cluster (r16, valid).
// ---------------------------------------------------------------------------
__global__ void selgather_kernel(const float* __restrict__ prob,
                                 const int* __restrict__ candCnt,
                                 const int* __restrict__ candIdx,
                                 const float* __restrict__ candVal,
                                 const float* __restrict__ zi,
                                 const float* __restrict__ zj,
                                 char* __restrict__ FT) {
  __shared__ float vals[MAXCAND];
  __shared__ int   idxs[MAXCAND];
  __shared__ int hist[256];
  __shared__ int pref[NPART + 1];
  __shared__ int cntL[NPART];
  __shared__ int topkL[KK];
  __shared__ int eqIdx[256];
  __shared__ int sChosen, sKrem, bad;
  const int c = blockIdx.x / GSUB, g = blockIdx.x - c * GSUB;
  const int t = threadIdx.x;

  if (t == 0) bad = 0;
  __syncthreads();
  if (t < NPART) {
    int cnt_p = candCnt[t * CC + c];
    cntL[t] = cnt_p;
    if (cnt_p > PCAP) bad = 1;
    int x = cnt_p;
#pragma unroll
    for (int d = 1; d < 64; d <<= 1) {
      int y = __shfl_up(x, d, 64);
      if (t >= d) x += y;
    }
    pref[t + 1] = x;
    if (t == 0) pref[0] = 0;
  }
  __syncthreads();
  const int total = pref[NPART];

  if (!bad && total >= KK && total <= MAXCAND) {
    for (int idx = t; idx < NPART * PCAP; idx += 256) {
      const int pt = idx >> 5, sl = idx & 31;
      if (sl < cntL[pt]) {
        const int o = pref[pt] + sl;
        vals[o] = candVal[(pt * CC + c) * PCAP + sl];
        idxs[o] = candIdx[(pt * CC + c) * PCAP + sl];
      }
    }
    __syncthreads();
    unsigned prefix = 0;
    int krem = KK;
    for (int pass = 0; pass < 4; ++pass) {
      const int shift = 24 - pass * 8;
      hist[t] = 0;
      __syncthreads();
      for (int j = t; j < total; j += 256) {
        unsigned u = __float_as_uint(vals[j]);
        bool match = (pass == 0) || ((u >> (shift + 8)) == (prefix >> (shift + 8)));
        if (match) atomicAdd(&hist[(u >> shift) & 255], 1);
      }
      __syncthreads();
      PICK_BIN()
      prefix |= ((unsigned)sChosen) << shift;
      krem = sKrem;
      __syncthreads();
    }
    const unsigned T = prefix;
    COMPACT_DET(total, __float_as_uint(vals[j]), idxs[j])
  } else {
    unsigned prefix = 0;
    int krem = KK;
    for (int pass = 0; pass < 4; ++pass) {
      const int shift = 24 - pass * 8;
      hist[t] = 0;
      __syncthreads();
      for (int i = t; i < BB; i += 256) {
        unsigned u = __float_as_uint(prob[i * CC + c]);
        bool match = (pass == 0) || ((u >> (shift + 8)) == (prefix >> (shift + 8)));
        if (match) atomicAdd(&hist[(u >> shift) & 255], 1);
      }
      __syncthreads();
      PICK_BIN()
      prefix |= ((unsigned)sChosen) << shift;
      krem = sKrem;
      __syncthreads();
    }
    const unsigned T = prefix;
    COMPACT_DET(BB, __float_as_uint(prob[(size_t)j * CC + c]), j)
  }

  // ---- Phase 2: gather rows [g*64, g*64+64); wave-per-row, 16 rows/wave ----
  __syncthreads();
  const int lane = t & 63, wv = t >> 6;
#pragma unroll 4
  for (int it = 0; it < 16; ++it) {
    const int p = g * 64 + wv * 16 + it;
    const int idx = topkL[p & (KK - 1)];
    const float* src = (p < KK ? zi : zj) + (size_t)idx * DD;
    float2 v = ((const float2*)src)[lane];
    float ss = fmaf(v.x, v.x, v.y * v.y);
#pragma unroll
    for (int m = 1; m < 64; m <<= 1) ss += __shfl_xor(ss, m, 64);
    const float scale = SQS / fmaxf(sqrtf(ss), 1e-8f);
    unsigned short ah = f2bf(v.x * scale), bh = f2bf(v.y * scale);
    unsigned hp = ((unsigned)bh << 16) | ah;
    const int gw = c * 256 + p;
    const int k2 = 2 * lane;
    const int kc = k2 >> 4;
    const int kk = k2 & 15;
    const size_t off = (size_t)(gw >> 5) * 8192 + (size_t)kc * 1024 +
                       (size_t)(((kk >> 3) * 32 + (gw & 31)) * 16 + (kk & 7) * 2);
    *(unsigned*)(FT + off) = hp;
  }
}

// ---------------------------------------------------------------------------
// Kernel 3: PANELIZED symmetric sim — BARRIER-FREE main loop. 4 waves/block,
// wave owns one 32-row A-group. Per iteration: TWO column-groups (two
// independent 8-MFMA chains interleaved -> latency hidden), B read straight
// from global (all 4 waves same addresses -> L1 broadcast; no LDS staging,
// no per-cg barriers). S = 4*nt is always even. launch_bounds(256,3) -> 3
// blocks/CU. Single __syncthreads before the cross-wave colLds merge.
// Math identical to r17 (absmax 0.0 lineage).
// ---------------------------------------------------------------------------
__global__ __launch_bounds__(256, 3) void sim_sym_kernel(
    const char* __restrict__ F, float* __restrict__ part,
    float* __restrict__ ownArr, float* __restrict__ posArr) {
  __shared__ float colLds[4][1024];
  const int tid = threadIdx.x;
  const int lane = tid & 63, wave = tid >> 6;
  const int lh2 = lane >> 5;
  const size_t lo16 = (size_t)lane * 16;
  f32x16 Z = {};

  if (blockIdx.x < NBLK * NCHUNK) {
    const int I = blockIdx.x / NCHUNK, q = blockIdx.x - I * NCHUNK;
    const int J0 = I + q * CHT;
    if (J0 >= NBLK) return;
    const int nt = min(CHT, NBLK - J0);
    const int S = nt * 4;                        // even (4*nt)
    const int G0 = J0 * 4;
    const int Ga = I * 4 + wave;

    bf16x8 A[8];
#pragma unroll
    for (int kc = 0; kc < 8; ++kc)
      A[kc] = *(const bf16x8*)(F + (size_t)Ga * 8192 + kc * 1024 + lo16);

    float rAcc[16];
#pragma unroll
    for (int r = 0; r < 16; ++r) rAcc[r] = 0.f;

    for (int s = 0; s < S; s += 2) {
      const char* g0 = F + (size_t)(G0 + s) * 8192;
      const char* g1 = F + (size_t)(G0 + s + 1) * 8192;
      f32x16 acc0 = Z, acc1 = Z;
#pragma unroll
      for (int kc = 0; kc < 8; ++kc) {
        bf16x8 b0 = *(const bf16x8*)(g0 + kc * 1024 + lo16);
        bf16x8 b1 = *(const bf16x8*)(g1 + kc * 1024 + lo16);
        acc0 = MFMA32(A[kc], b0, acc0);          // two independent chains
        acc1 = MFMA32(A[kc], b1, acc1);
      }
      float colv0 = 0.f, colv1 = 0.f;
#pragma unroll
      for (int r = 0; r < 16; ++r) {
        float e0 = __builtin_amdgcn_exp2f(acc0[r]);
        float e1 = __builtin_amdgcn_exp2f(acc1[r]);
        rAcc[r] += e0 + e1;
        colv0 += e0;
        colv1 += e1;
      }
      {
        float c0 = colv0 + __shfl_xor(colv0, 32, 64);
        float c1 = colv1 + __shfl_xor(colv1, 32, 64);
        if (lane < 32) {
          colLds[wave][s * 32 + lane] = c0;
          colLds[wave][(s + 1) * 32 + lane] = c1;
        }
      }
    }

    __syncthreads();                              // the ONLY block barrier
    for (int idx = tid; idx < S * 32; idx += 256) {
      const int J = J0 + (idx >> 7);
      if (J != I)
        part[(size_t)I * MM + J * 128 + (idx & 127)] =
            colLds[0][idx] + colLds[1][idx] + colLds[2][idx] + colLds[3][idx];
    }

#pragma unroll
    for (int m = 1; m < 32; m <<= 1)
#pragma unroll
      for (int r = 0; r < 16; ++r) rAcc[r] += __shfl_xor(rAcc[r], m, 32);
    if ((lane & 31) == 0) {
      const int rbase = I * 128 + wave * 32;
#pragma unroll
      for (int r = 0; r < 16; ++r) {
        const int rl = (r & 3) + 8 * (r >> 2) + 4 * lh2;
        part[(size_t)(NBLK + q) * MM + rbase + rl] = rAcc[r];
      }
    }
  } else {
    // ===== own/pos path: (c, half) blocks, 4 waves x 1 group, paired cgs =====
    const int bid2 = blockIdx.x - NBLK * NCHUNK;   // 0..199
    const int c = bid2 >> 1, half = bid2 & 1;
    const int Ga = c * 8 + half * 4 + wave;
    const int G0 = c * 8;

    bf16x8 A[8];
#pragma unroll
    for (int kc = 0; kc < 8; ++kc)
      A[kc] = *(const bf16x8*)(F + (size_t)Ga * 8192 + kc * 1024 + lo16);

    float rOwn[16], rPos[16];
#pragma unroll
    for (int r = 0; r < 16; ++r) { rOwn[r] = 0.f; rPos[r] = 0.f; }

    for (int s = 0; s < 8; s += 2) {
      const char* g0 = F + (size_t)(G0 + s) * 8192;
      const char* g1 = F + (size_t)(G0 + s + 1) * 8192;
      f32x16 acc0 = Z, acc1 = Z;
#pragma unroll
      for (int kc = 0; kc < 8; ++kc) {
        bf16x8 b0 = *(const bf16x8*)(g0 + kc * 1024 + lo16);
        bf16x8 b1 = *(const bf16x8*)(g1 + kc * 1024 + lo16);
        acc0 = MFMA32(A[kc], b0, acc0);
        acc1 = MFMA32(A[kc], b1, acc1);
      }
      const bool isPos = (s < 4);                  // cgs 0..3 = first 128 cols
#pragma unroll
      for (int r = 0; r < 16; ++r) {
        float e = __builtin_amdgcn_exp2f(acc0[r]) + __builtin_amdgcn_exp2f(acc1[r]);
        rOwn[r] += e;
        if (isPos) rPos[r] += e;
      }
    }

#pragma unroll
    for (int m = 1; m < 32; m <<= 1)
#pragma unroll
      for (int r = 0; r < 16; ++r) {
        rOwn[r] += __shfl_xor(rOwn[r], m, 32);
        rPos[r] += __shfl_xor(rPos[r], m, 32);
      }
    if ((lane & 31) == 0) {
      const int rbase = c * 256 + half * 128 + wave * 32;
#pragma unroll
      for (int r = 0; r < 16; ++r) {
        const int rl = (r & 3) + 8 * (r >> 2) + 4 * lh2;
        ownArr[rbase + rl] = rOwn[r];
        posArr[rbase + rl] = rPos[r];
      }
    }
  }
}

// ---------------------------------------------------------------------------
// Kernel 4: per-row loss + block reduction + last-block mean via ticket
// (r12/r16, validated; ticket contention is only 50 blocks).
// ---------------------------------------------------------------------------
__global__ void finalize_kernel(const float* __restrict__ part,
                                const float* __restrict__ ownArr,
                                const float* __restrict__ posArr,
                                float* __restrict__ partial,
                                int* __restrict__ ticket,
                                float* __restrict__ out) {
  __shared__ float red[4];
  const int t = threadIdx.x;
  const int p = blockIdx.x * 256 + t;
  const int pb = p >> 7;
  float a = 0.f;
  for (int b = 0; b < pb; ++b) a += part[(size_t)b * MM + p];
  const int qmax = (NBLK - 1 - pb) >> 3;
  for (int q = 0; q <= qmax; ++q) a += part[(size_t)(NBLK + q) * MM + p];
  float rl = logf(a - ownArr[p]) - logf(posArr[p]);
#pragma unroll
  for (int m = 1; m < 64; m <<= 1) rl += __shfl_xor(rl, m, 64);
  if ((t & 63) == 0) red[t >> 6] = rl;
  __syncthreads();
  if (t == 0) {
    const float bsum = red[0] + red[1] + red[2] + red[3];
    __hip_atomic_store(&partial[blockIdx.x], bsum, __ATOMIC_RELEASE,
                       __HIP_MEMORY_SCOPE_AGENT);
    const int old = __hip_atomic_fetch_add(ticket, 1, __ATOMIC_ACQ_REL,
                                           __HIP_MEMORY_SCOPE_AGENT);
    if (old == (MM / 256) - 1) {
      float s = 0.f;
      for (int i = 0; i < MM / 256; ++i)
        s += __hip_atomic_load(&partial[i], __ATOMIC_ACQUIRE,
                               __HIP_MEMORY_SCOPE_AGENT);
      out[0] = s * (1.0f / MM);
    }
  }
}

extern "C" void kernel_launch(void* const* d_in, const int* in_sizes, int n_in,
                              void* d_out, int out_size, void* d_ws, size_t ws_size,
                              hipStream_t stream) {
  const float* prob = (const float*)d_in[0];
  const float* zi   = (const float*)d_in[1];
  const float* zj   = (const float*)d_in[2];
  float* out = (float*)d_out;

  char* ws = (char*)d_ws;
  char*  FT       = ws;                                  // 3,276,800 B
  float* part     = (float*)(ws + 3276800);              // 113*12800*4 = 5,785,600 B
  // cand buffers alias the (not-yet-live) part region: dead before sim writes.
  int*   candCnt  = (int*)  (ws + 3276800);              //    12,800 B
  int*   candIdx  = (int*)  (ws + 3276800 + 16384);      //   409,600 B
  float* candVal  = (float*)(ws + 3276800 + 430080);     //   409,600 B
  float* ownArr   = (float*)(ws + 9062400);              //    51,200 B
  float* posArr   = (float*)(ws + 9113600);              //    51,200 B
  float* partial  = (float*)(ws + 9164800);              //       256 B
  int*   ticket   = (int*)  (ws + 9165056);              //         4 B

  cand_kernel     <<<NPART, 256, 0, stream>>>(prob, candCnt, candIdx, candVal, ticket);
  selgather_kernel<<<CC * GSUB, 256, 0, stream>>>(prob, candCnt, candIdx, candVal, zi, zj, FT);
  sim_sym_kernel  <<<NBLK * NCHUNK + 2 * CC, 256, 0, stream>>>(FT, part, ownArr, posArr);
  finalize_kernel <<<MM / 256, 256, 0, stream>>>(part, ownArr, posArr, partial, ticket, out);
}

// Round 19
// 86.489 us; speedup vs baseline: 1.3034x; 1.2578x over previous
//
#include <hip/hip_runtime.h>
#include <math.h>

#define BB 16384      // B
#define CC 50         // clusters
#define KK 128        // top-K
#define DD 128        // feature dim
#define MM 12800      // CC*2*KK rows of F
#define NBLK 100      // 128-row blocks of F
#define NCHUNK 13     // J-chunks per row (chunk = 8 tiles)
#define CHT 8         // tiles per chunk
#define MAXCAND 2048
#define TCAND 0.97f
#define NPART 64      // candidate partitions (256 rows each)
#define RPP 256       // rows per partition
#define PCAP 32       // per (partition,cluster) capacity; expected ~7.7
#define GSUB 8        // sub-blocks per cluster in selgather (redundant select)
#define NFINB 200     // finalize blocks (64 rows each)
// F rows pre-scaled by SQS = sqrt(2/ln2): dot(F,F) = sim*2/ln2 -> exp2 direct.
// Single bf16 product (validated r8-r18: absmax 0.0 vs reference).
#define SQS 1.6986436f

// Tiled F layout: for each 32-row group G (400 groups), each kc (16-K chunk,
// 8 chunks), 64 granules of 16B lane-ordered for mfma_32x32x16_bf16 operands.
//
// LESSON (r13/r14): intra-kernel producer->consumer sync costs a per-block
// device-fence L2-writeback tax — keep pipeline stages as separate nodes.
// LESSON (r16): node count is ~free; kernel-time sum + a ~45us harness fill
// per replay dominate. This round: parallelize the latency-starved small
// kernels (finalize x4 blocks, selgather gather x2 blocks); sim unchanged.

typedef __bf16 bf16x8 __attribute__((ext_vector_type(8)));
typedef float f32x16 __attribute__((ext_vector_type(16)));

#define MFMA32(a, b, c) __builtin_amdgcn_mfma_f32_32x32x16_bf16(a, b, c, 0, 0, 0)

__device__ inline unsigned short f2bf(float x) {
  unsigned u = __float_as_uint(x);
  unsigned r = (u + 0x7fffu + ((u >> 16) & 1u)) >> 16;
  return (unsigned short)r;
}

// ---------------------------------------------------------------------------
// Kernel 1: candidate collection (r9, validated).
// ---------------------------------------------------------------------------
__global__ void cand_kernel(const float* __restrict__ prob, int* __restrict__ candCnt,
                            int* __restrict__ candIdx, float* __restrict__ candVal) {
  __shared__ int lcnt[CC];
  const int b = blockIdx.x, t = threadIdx.x;
  if (t < CC) lcnt[t] = 0;
  __syncthreads();
  const int base = b * RPP * CC;
  for (int i = t; i < RPP * CC; i += 256) {
    const float v = prob[base + i];
    if (v >= TCAND) {
      const int r = i / CC, c = i - r * CC;
      const int slot = atomicAdd(&lcnt[c], 1);
      if (slot < PCAP) {
        candIdx[(b * CC + c) * PCAP + slot] = b * RPP + r;
        candVal[(b * CC + c) * PCAP + slot] = v;
      }
    }
  }
  __syncthreads();
  if (t < CC) candCnt[b * CC + t] = lcnt[t];
}

// ---------------------------------------------------------------------------
// PARALLEL bin selection (r12, validated).
// ---------------------------------------------------------------------------
#define PICK_BIN()                                                             \
  {                                                                            \
    _Pragma("unroll")                                                          \
    for (int d = 1; d < 256; d <<= 1) {                                        \
      int v = (t + d < 256) ? hist[t + d] : 0;                                 \
      __syncthreads();                                                         \
      hist[t] += v;                                                            \
      __syncthreads();                                                         \
    }                                                                          \
    const int Sb = hist[t];                                                    \
    const int Sb1 = (t == 255) ? 0 : hist[t + 1];                              \
    if (Sb >= krem && Sb1 < krem) { sChosen = t; sKrem = krem - Sb1; }         \
    __syncthreads();                                                           \
  }

// Deterministic scan-based compaction (r16, validated).
#define COMPACT_DET(TOTAL, GETU, GETI)                                         \
  {                                                                            \
    const int chunk = ((TOTAL) + 255) >> 8;                                    \
    const int j0 = t * chunk;                                                  \
    const int j1 = (j0 + chunk < (TOTAL)) ? j0 + chunk : (TOTAL);              \
    int myGt = 0, myEq = 0;                                                    \
    for (int j = j0; j < j1; ++j) {                                            \
      unsigned u = (GETU);                                                     \
      myGt += (u > T) ? 1 : 0; myEq += (u == T) ? 1 : 0;                       \
    }                                                                          \
    hist[t] = (myGt << 16) | myEq;                                             \
    __syncthreads();                                                           \
    _Pragma("unroll")                                                          \
    for (int d = 1; d < 256; d <<= 1) {                                        \
      int v = (t >= d) ? hist[t - d] : 0;                                      \
      __syncthreads();                                                         \
      hist[t] += v;                                                            \
      __syncthreads();                                                         \
    }                                                                          \
    const int incl = hist[t];                                                  \
    const int gtCount = (hist[255] >> 16) & 0xffff;                            \
    const int eqTotal = hist[255] & 0xffff;                                    \
    int pg = ((incl >> 16) & 0xffff) - myGt;                                   \
    int pe = (incl & 0xffff) - myEq;                                           \
    for (int j = j0; j < j1; ++j) {                                            \
      unsigned u = (GETU);                                                     \
      if (u > T) topkL[pg++] = (GETI);                                         \
      else if (u == T) { if (pe < 256) eqIdx[pe] = (GETI); pe++; }             \
    }                                                                          \
    __syncthreads();                                                           \
    if (t == 0) {                                                              \
      int krem2 = KK - gtCount;                                                \
      int ec = eqTotal < 256 ? eqTotal : 256;                                  \
      for (int j2 = 0; j2 < krem2; ++j2) {                                     \
        int bi = -1, bv = 0x7fffffff;                                          \
        for (int q = 0; q < ec; ++q) {                                         \
          int v = eqIdx[q];                                                    \
          if (v >= 0 && v < bv) { bv = v; bi = q; }                            \
        }                                                                      \
        topkL[gtCount + j2] = bv;                                              \
        eqIdx[bi] = -1;                                                        \
      }                                                                        \
    }                                                                          \
  }

// ---------------------------------------------------------------------------
// Kernel 2: FUSED top-K select + gather/norm, GSUB=8 blocks/cluster.
// Each block redundantly computes the identical topkL (deterministic),
// then gathers its 32-row slice (8 rows/wave) -> 400-block gather phase.
// ---------------------------------------------------------------------------
__global__ void selgather_kernel(const float* __restrict__ prob,
                                 const int* __restrict__ candCnt,
                                 const int* __restrict__ candIdx,
                                 const float* __restrict__ candVal,
                                 const float* __restrict__ zi,
                                 const float* __restrict__ zj,
                                 char* __restrict__ FT) {
  __shared__ float vals[MAXCAND];
  __shared__ int   idxs[MAXCAND];
  __shared__ int hist[256];
  __shared__ int pref[NPART + 1];
  __shared__ int cntL[NPART];
  __shared__ int topkL[KK];
  __shared__ int eqIdx[256];
  __shared__ int sChosen, sKrem, bad;
  const int c = blockIdx.x / GSUB, g = blockIdx.x - c * GSUB;
  const int t = threadIdx.x;

  if (t == 0) bad = 0;
  __syncthreads();
  if (t < NPART) {
    int cnt_p = candCnt[t * CC + c];
    cntL[t] = cnt_p;
    if (cnt_p > PCAP) bad = 1;
    int x = cnt_p;
#pragma unroll
    for (int d = 1; d < 64; d <<= 1) {
      int y = __shfl_up(x, d, 64);
      if (t >= d) x += y;
    }
    pref[t + 1] = x;
    if (t == 0) pref[0] = 0;
  }
  __syncthreads();
  const int total = pref[NPART];

  if (!bad && total >= KK && total <= MAXCAND) {
    for (int idx = t; idx < NPART * PCAP; idx += 256) {
      const int pt = idx >> 5, sl = idx & 31;
      if (sl < cntL[pt]) {
        const int o = pref[pt] + sl;
        vals[o] = candVal[(pt * CC + c) * PCAP + sl];
        idxs[o] = candIdx[(pt * CC + c) * PCAP + sl];
      }
    }
    __syncthreads();
    unsigned prefix = 0;
    int krem = KK;
    for (int pass = 0; pass < 4; ++pass) {
      const int shift = 24 - pass * 8;
      hist[t] = 0;
      __syncthreads();
      for (int j = t; j < total; j += 256) {
        unsigned u = __float_as_uint(vals[j]);
        bool match = (pass == 0) || ((u >> (shift + 8)) == (prefix >> (shift + 8)));
        if (match) atomicAdd(&hist[(u >> shift) & 255], 1);
      }
      __syncthreads();
      PICK_BIN()
      prefix |= ((unsigned)sChosen) << shift;
      krem = sKrem;
      __syncthreads();
    }
    const unsigned T = prefix;
    COMPACT_DET(total, __float_as_uint(vals[j]), idxs[j])
  } else {
    unsigned prefix = 0;
    int krem = KK;
    for (int pass = 0; pass < 4; ++pass) {
      const int shift = 24 - pass * 8;
      hist[t] = 0;
      __syncthreads();
      for (int i = t; i < BB; i += 256) {
        unsigned u = __float_as_uint(prob[i * CC + c]);
        bool match = (pass == 0) || ((u >> (shift + 8)) == (prefix >> (shift + 8)));
        if (match) atomicAdd(&hist[(u >> shift) & 255], 1);
      }
      __syncthreads();
      PICK_BIN()
      prefix |= ((unsigned)sChosen) << shift;
      krem = sKrem;
      __syncthreads();
    }
    const unsigned T = prefix;
    COMPACT_DET(BB, __float_as_uint(prob[(size_t)j * CC + c]), j)
  }

  // ---- Phase 2: gather rows [g*32, g*32+32); 8 rows per wave ----
  __syncthreads();
  const int lane = t & 63, wv = t >> 6;
#pragma unroll 4
  for (int it = 0; it < 8; ++it) {
    const int p = g * 32 + wv * 8 + it;
    const int idx = topkL[p & (KK - 1)];
    const float* src = (p < KK ? zi : zj) + (size_t)idx * DD;
    float2 v = ((const float2*)src)[lane];
    float ss = fmaf(v.x, v.x, v.y * v.y);
#pragma unroll
    for (int m = 1; m < 64; m <<= 1) ss += __shfl_xor(ss, m, 64);
    const float scale = SQS / fmaxf(sqrtf(ss), 1e-8f);
    unsigned short ah = f2bf(v.x * scale), bh = f2bf(v.y * scale);
    unsigned hp = ((unsigned)bh << 16) | ah;
    const int gw = c * 256 + p;
    const int k2 = 2 * lane;
    const int kc = k2 >> 4;
    const int kk = k2 & 15;
    const size_t off = (size_t)(gw >> 5) * 8192 + (size_t)kc * 1024 +
                       (size_t)(((kk >> 3) * 32 + (gw & 31)) * 16 + (kk & 7) * 2);
    *(unsigned*)(FT + off) = hp;
  }
}

// ---------------------------------------------------------------------------
// Kernel 3: PANELIZED symmetric sim, barrier-free main loop (r18, validated).
// ---------------------------------------------------------------------------
__global__ __launch_bounds__(256, 3) void sim_sym_kernel(
    const char* __restrict__ F, float* __restrict__ part,
    float* __restrict__ ownArr, float* __restrict__ posArr) {
  __shared__ float colLds[4][1024];
  const int tid = threadIdx.x;
  const int lane = tid & 63, wave = tid >> 6;
  const int lh2 = lane >> 5;
  const size_t lo16 = (size_t)lane * 16;
  f32x16 Z = {};

  if (blockIdx.x < NBLK * NCHUNK) {
    const int I = blockIdx.x / NCHUNK, q = blockIdx.x - I * NCHUNK;
    const int J0 = I + q * CHT;
    if (J0 >= NBLK) return;
    const int nt = min(CHT, NBLK - J0);
    const int S = nt * 4;                        // even (4*nt)
    const int G0 = J0 * 4;
    const int Ga = I * 4 + wave;

    bf16x8 A[8];
#pragma unroll
    for (int kc = 0; kc < 8; ++kc)
      A[kc] = *(const bf16x8*)(F + (size_t)Ga * 8192 + kc * 1024 + lo16);

    float rAcc[16];
#pragma unroll
    for (int r = 0; r < 16; ++r) rAcc[r] = 0.f;

    for (int s = 0; s < S; s += 2) {
      const char* g0 = F + (size_t)(G0 + s) * 8192;
      const char* g1 = F + (size_t)(G0 + s + 1) * 8192;
      f32x16 acc0 = Z, acc1 = Z;
#pragma unroll
      for (int kc = 0; kc < 8; ++kc) {
        bf16x8 b0 = *(const bf16x8*)(g0 + kc * 1024 + lo16);
        bf16x8 b1 = *(const bf16x8*)(g1 + kc * 1024 + lo16);
        acc0 = MFMA32(A[kc], b0, acc0);
        acc1 = MFMA32(A[kc], b1, acc1);
      }
      float colv0 = 0.f, colv1 = 0.f;
#pragma unroll
      for (int r = 0; r < 16; ++r) {
        float e0 = __builtin_amdgcn_exp2f(acc0[r]);
        float e1 = __builtin_amdgcn_exp2f(acc1[r]);
        rAcc[r] += e0 + e1;
        colv0 += e0;
        colv1 += e1;
      }
      {
        float c0 = colv0 + __shfl_xor(colv0, 32, 64);
        float c1 = colv1 + __shfl_xor(colv1, 32, 64);
        if (lane < 32) {
          colLds[wave][s * 32 + lane] = c0;
          colLds[wave][(s + 1) * 32 + lane] = c1;
        }
      }
    }

    __syncthreads();
    for (int idx = tid; idx < S * 32; idx += 256) {
      const int J = J0 + (idx >> 7);
      if (J != I)
        part[(size_t)I * MM + J * 128 + (idx & 127)] =
            colLds[0][idx] + colLds[1][idx] + colLds[2][idx] + colLds[3][idx];
    }

#pragma unroll
    for (int m = 1; m < 32; m <<= 1)
#pragma unroll
      for (int r = 0; r < 16; ++r) rAcc[r] += __shfl_xor(rAcc[r], m, 32);
    if ((lane & 31) == 0) {
      const int rbase = I * 128 + wave * 32;
#pragma unroll
      for (int r = 0; r < 16; ++r) {
        const int rl = (r & 3) + 8 * (r >> 2) + 4 * lh2;
        part[(size_t)(NBLK + q) * MM + rbase + rl] = rAcc[r];
      }
    }
  } else {
    const int bid2 = blockIdx.x - NBLK * NCHUNK;   // 0..199
    const int c = bid2 >> 1, half = bid2 & 1;
    const int Ga = c * 8 + half * 4 + wave;
    const int G0 = c * 8;

    bf16x8 A[8];
#pragma unroll
    for (int kc = 0; kc < 8; ++kc)
      A[kc] = *(const bf16x8*)(F + (size_t)Ga * 8192 + kc * 1024 + lo16);

    float rOwn[16], rPos[16];
#pragma unroll
    for (int r = 0; r < 16; ++r) { rOwn[r] = 0.f; rPos[r] = 0.f; }

    for (int s = 0; s < 8; s += 2) {
      const char* g0 = F + (size_t)(G0 + s) * 8192;
      const char* g1 = F + (size_t)(G0 + s + 1) * 8192;
      f32x16 acc0 = Z, acc1 = Z;
#pragma unroll
      for (int kc = 0; kc < 8; ++kc) {
        bf16x8 b0 = *(const bf16x8*)(g0 + kc * 1024 + lo16);
        bf16x8 b1 = *(const bf16x8*)(g1 + kc * 1024 + lo16);
        acc0 = MFMA32(A[kc], b0, acc0);
        acc1 = MFMA32(A[kc], b1, acc1);
      }
      const bool isPos = (s < 4);
#pragma unroll
      for (int r = 0; r < 16; ++r) {
        float e = __builtin_amdgcn_exp2f(acc0[r]) + __builtin_amdgcn_exp2f(acc1[r]);
        rOwn[r] += e;
        if (isPos) rPos[r] += e;
      }
    }

#pragma unroll
    for (int m = 1; m < 32; m <<= 1)
#pragma unroll
      for (int r = 0; r < 16; ++r) {
        rOwn[r] += __shfl_xor(rOwn[r], m, 32);
        rPos[r] += __shfl_xor(rPos[r], m, 32);
      }
    if ((lane & 31) == 0) {
      const int rbase = c * 256 + half * 128 + wave * 32;
#pragma unroll
      for (int r = 0; r < 16; ++r) {
        const int rl = (r & 3) + 8 * (r >> 2) + 4 * lh2;
        ownArr[rbase + rl] = rOwn[r];
        posArr[rbase + rl] = rPos[r];
      }
    }
  }
}

// ---------------------------------------------------------------------------
// Kernel 4: per-row loss, NFINB=200 blocks x 64 rows. 4 threads/row split the
// slot sum mod 4, combine via width-4 shuffles (deterministic fixed order).
// ---------------------------------------------------------------------------
__global__ void finalize_kernel(const float* __restrict__ part,
                                const float* __restrict__ ownArr,
                                const float* __restrict__ posArr,
                                float* __restrict__ partial) {
  __shared__ float red[4];
  const int t = threadIdx.x;
  const int p = blockIdx.x * 64 + (t >> 2);
  const int sub = t & 3;
  const int pb = p >> 7;
  float a = 0.f;
  for (int b = sub; b < pb; b += 4) a += part[(size_t)b * MM + p];
  const int qmax = (NBLK - 1 - pb) >> 3;
  for (int q = sub; q <= qmax; q += 4) a += part[(size_t)(NBLK + q) * MM + p];
  a += __shfl_xor(a, 1, 4);
  a += __shfl_xor(a, 2, 4);
  float rl = (sub == 0) ? (logf(a - ownArr[p]) - logf(posArr[p])) : 0.f;
#pragma unroll
  for (int m = 1; m < 64; m <<= 1) rl += __shfl_xor(rl, m, 64);
  if ((t & 63) == 0) red[t >> 6] = rl;
  __syncthreads();
  if (t == 0) partial[blockIdx.x] = red[0] + red[1] + red[2] + red[3];
}

// ---------------------------------------------------------------------------
// Kernel 5: mean over NFINB partials -> scalar (deterministic fixed order).
// ---------------------------------------------------------------------------
__global__ void mean_kernel(const float* __restrict__ partial, float* __restrict__ out) {
  const int t = threadIdx.x;   // 64 threads
  float s = 0.f;
  for (int i = t; i < NFINB; i += 64) s += partial[i];
#pragma unroll
  for (int m = 1; m < 64; m <<= 1) s += __shfl_xor(s, m, 64);
  if (t == 0) out[0] = s * (1.0f / MM);
}

extern "C" void kernel_launch(void* const* d_in, const int* in_sizes, int n_in,
                              void* d_out, int out_size, void* d_ws, size_t ws_size,
                              hipStream_t stream) {
  const float* prob = (const float*)d_in[0];
  const float* zi   = (const float*)d_in[1];
  const float* zj   = (const float*)d_in[2];
  float* out = (float*)d_out;

  char* ws = (char*)d_ws;
  char*  FT       = ws;                                  // 3,276,800 B
  float* part     = (float*)(ws + 3276800);              // 113*12800*4 = 5,785,600 B
  // cand buffers alias the (not-yet-live) part region: dead before sim writes.
  int*   candCnt  = (int*)  (ws + 3276800);              //    12,800 B
  int*   candIdx  = (int*)  (ws + 3276800 + 16384);      //   409,600 B
  float* candVal  = (float*)(ws + 3276800 + 430080);     //   409,600 B
  float* ownArr   = (float*)(ws + 9062400);              //    51,200 B
  float* posArr   = (float*)(ws + 9113600);              //    51,200 B
  float* partial  = (float*)(ws + 9164800);              //       800 B

  cand_kernel     <<<NPART, 256, 0, stream>>>(prob, candCnt, candIdx, candVal);
  selgather_kernel<<<CC * GSUB, 256, 0, stream>>>(prob, candCnt, candIdx, candVal, zi, zj, FT);
  sim_sym_kernel  <<<NBLK * NCHUNK + 2 * CC, 256, 0, stream>>>(FT, part, ownArr, posArr);
  finalize_kernel <<<NFINB, 256, 0, stream>>>(part, ownArr, posArr, partial);
  mean_kernel     <<<1, 64, 0, stream>>>(partial, out);
}